// Round 4
// baseline (731.243 us; speedup 1.0000x reference)
//
#include <hip/hip_runtime.h>

// RotarySelfAttention on MI355X (gfx950).
// Round 3: hide global latency in k_attn + kill the V-transpose cost.
//   - k_vcast: past V fp32 -> bf16, TRANSPOSED vpT[b][h][d][j] (zeros for j>=Lp).
//     Attention V staging becomes pure vector copy (no split, no LDS transpose).
//   - prefetch ISSUED AFTER barrier [A] (full-iteration distance before the
//     vmcnt(0) drain at the next barrier, instead of zero distance).
//   - native (__bf16) casts; unmasked softmax fast path for non-final tiles.
//   - LDS 36864 -> 27648 B. k_qkv: Q/K use 2 MFMAs per pair (V keeps 3).

typedef unsigned short u16;
typedef unsigned int   u32;
typedef float  f32x4  __attribute__((ext_vector_type(4)));
typedef __bf16 bf16x8 __attribute__((ext_vector_type(8)));

#define DEV static __device__ __forceinline__

constexpr int NP = 3584;

DEV u16 cvt1(float f){ return __builtin_bit_cast(u16, (__bf16)f); }
DEV float bf2f(u16 h){ return __uint_as_float((u32)h << 16); }
DEV void split2(float f, u16 &h, u16 &l){ h = cvt1(f); l = cvt1(f - bf2f(h)); }

DEV f32x4 mfma16(bf16x8 a, bf16x8 b, f32x4 c){
  return __builtin_amdgcn_mfma_f32_16x16x32_bf16(a, b, c, 0, 0, 0);
}

// ---------------- split x into hi/lo bf16 ----------------
__global__ __launch_bounds__(256) void k_split_x(const float* __restrict__ x,
                                                 u16* __restrict__ xh, u16* __restrict__ xl){
  int i = blockIdx.x * 256 + threadIdx.x;
  float4 v = ((const float4*)x)[i];
  u16 h0,l0,h1,l1,h2,l2,h3,l3;
  split2(v.x,h0,l0); split2(v.y,h1,l1); split2(v.z,h2,l2); split2(v.w,h3,l3);
  ushort4 hv; hv.x=h0; hv.y=h1; hv.z=h2; hv.w=h3;
  ushort4 lv; lv.x=l0; lv.y=l1; lv.z=l2; lv.w=l3;
  ((ushort4*)xh)[i] = hv; ((ushort4*)xl)[i] = lv;
}

// ------------- transpose + split weights: Wt[n][k] = W[k][n] -------------
__global__ __launch_bounds__(256) void k_wsplit(const float* __restrict__ w0, const float* __restrict__ w1,
                                                const float* __restrict__ w2, const float* __restrict__ w3,
                                                u16* __restrict__ Wth, u16* __restrict__ Wtl){
  __shared__ float tl[64][65];
  int z = blockIdx.z;
  const float* W = (z==0) ? w0 : (z==1) ? w1 : (z==2) ? w2 : w3;
  u16* oh = Wth + (size_t)z * (1024*1024);
  u16* ol = Wtl + (size_t)z * (1024*1024);
  int n0 = blockIdx.x*64, k0 = blockIdx.y*64;
  int tid = threadIdx.x;
  #pragma unroll
  for (int i=0;i<16;++i){
    int idx = i*256 + tid; int rr = idx >> 6, cc = idx & 63;
    tl[rr][cc] = W[(size_t)(k0+rr)*1024 + n0 + cc];
  }
  __syncthreads();
  #pragma unroll
  for (int i=0;i<16;++i){
    int idx = i*256 + tid; int rr = idx >> 6, cc = idx & 63;
    u16 h,l; split2(tl[cc][rr], h, l);
    size_t o = (size_t)(n0+rr)*1024 + k0 + cc;
    oh[o] = h; ol[o] = l;
  }
}

// -------- past V: fp32 -> bf16, transposed vpT[b][h][d][j], zero j>=Lp --------
__global__ __launch_bounds__(256) void k_vcast(const float* __restrict__ pv,
                                               const int* __restrict__ plen,
                                               u16* __restrict__ vpT){
  int jt = blockIdx.x, h = blockIdx.y, b = blockIdx.z;
  int Lp = min(max(plen[b],0), NP);
  int jend = min((Lp+63) & ~63, NP);
  int j0 = jt*64;
  if (j0 >= jend) return;
  __shared__ u16 t[64*72];
  int tid = threadIdx.x;
  int j = tid>>2, c4 = tid&3;
  size_t src = (size_t)(b*16+h)*NP*64 + (size_t)(j0+j)*64;
  bool live = (j0 + j) < Lp;
  #pragma unroll
  for (int k=0;k<4;++k){
    int d = c4*16 + k*4;
    float4 v;
    if (live) v = *(const float4*)&pv[src + d];
    else { v.x=0.f; v.y=0.f; v.z=0.f; v.w=0.f; }
    ushort4 hv; hv.x=cvt1(v.x); hv.y=cvt1(v.y); hv.z=cvt1(v.z); hv.w=cvt1(v.w);
    *(ushort4*)&t[j*72 + d] = hv;
  }
  __syncthreads();
  size_t dst = (size_t)(b*16+h)*64*NP;
  int vd = tid>>3, vj8 = (tid&7)*8;
  #pragma unroll
  for (int k=0;k<2;++k){
    int d = vd + k*32;
    u16 tmp[8];
    #pragma unroll
    for (int i=0;i<8;++i) tmp[i] = t[(vj8+i)*72 + d];
    *(uint4*)&vpT[dst + (size_t)d*NP + j0 + vj8] = *(uint4*)tmp;
  }
}

// ---------------- QKV projection GEMM + bias + RoPE + mask ----------------
__global__ __launch_bounds__(256) void k_qkv(
    const u16* __restrict__ xh, const u16* __restrict__ xl,
    const u16* __restrict__ Wth, const u16* __restrict__ Wtl,
    const float* __restrict__ bq, const float* __restrict__ bk, const float* __restrict__ bv,
    const float* __restrict__ rcos, const float* __restrict__ rsin,
    const int* __restrict__ cnts,
    u16* __restrict__ qh, u16* __restrict__ ql,
    u16* __restrict__ kh, u16* __restrict__ vh)
{
  int zi = blockIdx.z;
  int n0 = blockIdx.x * 128, m0 = blockIdx.y * 128;
  int b = m0 >> 9, t0 = m0 & 511;
  int cnt = cnts[b];
  if (t0 >= cnt) return;
  const u16* Bh = Wth + (size_t)zi * (1024*1024);
  const u16* Bl = Wtl + (size_t)zi * (1024*1024);
  const float* bias = (zi==0) ? bq : (zi==1) ? bk : bv;
  u16* oh = (zi==0) ? qh : (zi==1) ? kh : vh;
  u16* ol = ql;
  bool wlo = (zi == 2);    // only V keeps the x-hi * w-lo correction

  __shared__ u16 sA[2][128*40];
  __shared__ u16 sB[2][128*40];

  int tid = threadIdx.x, lane = tid & 63, wid = tid >> 6;
  int r = lane & 15, quad = lane >> 4;
  int wm = (wid >> 1) * 64, wn = (wid & 1) * 64;

  const f32x4 fz = {0.f,0.f,0.f,0.f};
  f32x4 acc[4][4];
  #pragma unroll
  for (int i=0;i<4;++i){
    #pragma unroll
    for (int j=0;j<4;++j) acc[i][j] = fz;
  }

  int srow = tid >> 2, sc8 = (tid & 3) * 8;

  for (int kt = 0; kt < 32; ++kt){
    int kb = kt * 32;
    __syncthreads();
    {
      size_t ga  = (size_t)(m0 + srow) * 1024 + kb + sc8;
      size_t gb  = (size_t)(n0 + srow) * 1024 + kb + sc8;
      int lo = srow*40 + sc8, lo2 = lo + 64*40;
      *(uint4*)&sA[0][lo]  = *(const uint4*)&xh[ga];
      *(uint4*)&sA[1][lo]  = *(const uint4*)&xl[ga];
      *(uint4*)&sB[0][lo]  = *(const uint4*)&Bh[gb];
      *(uint4*)&sB[1][lo]  = *(const uint4*)&Bl[gb];
      *(uint4*)&sA[0][lo2] = *(const uint4*)&xh[ga + 64*1024];
      *(uint4*)&sA[1][lo2] = *(const uint4*)&xl[ga + 64*1024];
      *(uint4*)&sB[0][lo2] = *(const uint4*)&Bh[gb + 64*1024];
      *(uint4*)&sB[1][lo2] = *(const uint4*)&Bl[gb + 64*1024];
    }
    __syncthreads();
    bf16x8 ah[4], al[4], bh8[4], bl8[4];
    #pragma unroll
    for (int mf=0; mf<4; ++mf){
      int off = (wm + mf*16 + r)*40 + quad*8;
      ah[mf] = *(const bf16x8*)&sA[0][off];
      al[mf] = *(const bf16x8*)&sA[1][off];
    }
    #pragma unroll
    for (int nf=0; nf<4; ++nf){
      int off = (wn + nf*16 + r)*40 + quad*8;
      bh8[nf] = *(const bf16x8*)&sB[0][off];
      if (wlo) bl8[nf] = *(const bf16x8*)&sB[1][off];
    }
    #pragma unroll
    for (int mf=0; mf<4; ++mf){
      #pragma unroll
      for (int nf=0; nf<4; ++nf){
        acc[mf][nf] = mfma16(ah[mf], bh8[nf], acc[mf][nf]);
        acc[mf][nf] = mfma16(al[mf], bh8[nf], acc[mf][nf]);
        if (wlo) acc[mf][nf] = mfma16(ah[mf], bl8[nf], acc[mf][nf]);
      }
    }
  }

  float vals[4][4][4];
  #pragma unroll
  for (int mf=0;mf<4;++mf){
    #pragma unroll
    for (int nf=0;nf<4;++nf){
      float bb = bias[n0 + wn + nf*16 + r];
      #pragma unroll
      for (int e=0;e<4;++e) vals[mf][nf][e] = acc[mf][nf][e] + bb;
    }
  }
  if (zi < 2){
    #pragma unroll
    for (int mf=0;mf<4;++mf){
      #pragma unroll
      for (int e=0;e<4;++e){
        int t = t0 + wm + mf*16 + quad*4 + e;
        #pragma unroll
        for (int nf=0;nf<2;++nf){
          int d = nf*16 + r;
          float c1 = rcos[t*64 + d],      s1 = rsin[t*64 + d];
          float c2 = rcos[t*64 + d + 32], s2 = rsin[t*64 + d + 32];
          float x1 = vals[mf][nf][e], x2 = vals[mf][nf+2][e];
          vals[mf][nf][e]   = x1*c1 - x2*s1;
          vals[mf][nf+2][e] = x2*c2 + x1*s2;
        }
      }
    }
  }
  #pragma unroll
  for (int mf=0;mf<4;++mf){
    #pragma unroll
    for (int e=0;e<4;++e){
      int t = t0 + wm + mf*16 + quad*4 + e;
      float msk = (t < cnt) ? 1.f : 0.f;
      #pragma unroll
      for (int nf=0;nf<4;++nf){
        int gc = n0 + wn + nf*16 + r;
        int head = gc >> 6, d = gc & 63;
        float v = vals[mf][nf][e] * msk;
        u16 hh, ll; split2(v, hh, ll);
        size_t o = ((size_t)(b*16 + head)*512 + t)*64 + d;
        oh[o] = hh;
        if (zi == 0) ol[o] = ll;
      }
    }
  }
}

// -------- flash attention, split-K, fixed-max softmax, early prefetch --------
__global__ __launch_bounds__(256,4) void k_attn(
    const u16* __restrict__ qh_, const u16* __restrict__ ql_,
    const u16* __restrict__ knh, const u16* __restrict__ vnh,
    const float* __restrict__ pk, const u16* __restrict__ vpT,
    const int* __restrict__ plen, const int* __restrict__ cnts,
    int S, float* __restrict__ pl, float* __restrict__ pO)
{
  int qt = blockIdx.x, h = blockIdx.y;
  int zb = blockIdx.z;
  int b = zb / S, s = zb - b * S;
  int cnt = cnts[b];
  int q0 = qt * 128;
  if (q0 >= cnt) return;
  int Lp = min(max(plen[b], 0), NP);
  int TL = Lp + cnt;
  int Ln = max(0, TL - NP);
  int jend = min((Lp + 63) & ~63, NP);
  int minTLP = min(TL, NP);
  int Zar = max(0, minTLP - jend);
  int npast = jend >> 6, nnew = (Ln + 63) >> 6;
  int Tt = npast + nnew;
  int qsp = (Tt + S - 1) / S;
  int it0 = s * qsp, it1 = min(Tt, it0 + qsp);
  bool hasZ = (s == 0 && Zar > 0);
  if (it0 >= it1 && !hasZ) return;

  __shared__ u16 sK [64*72];
  __shared__ u16 sVT[64*72];
  __shared__ u16 sP [4*32*72];

  int tid = threadIdx.x, lane = tid & 63, wid = tid >> 6;
  int r = lane & 15, quad = lane >> 4;
  int wm0 = wid * 32;

  bf16x8 Qh[2][2], Ql[2][2];
  size_t qbase = ((size_t)(b*16 + h)*512 + q0 + wm0) * 64;
  #pragma unroll
  for (int mf=0;mf<2;++mf){
    #pragma unroll
    for (int ks=0;ks<2;++ks){
      size_t o = qbase + (size_t)(mf*16 + r)*64 + ks*32 + quad*8;
      Qh[mf][ks] = *(const bf16x8*)&qh_[o];
      Ql[mf][ks] = *(const bf16x8*)&ql_[o];
    }
  }

  const f32x4 fz = {0.f,0.f,0.f,0.f};
  f32x4 O[2][4];
  float lsum[2][4];
  #pragma unroll
  for (int mf=0;mf<2;++mf){
    #pragma unroll
    for (int e=0;e<4;++e) lsum[mf][e] = 0.f;
    #pragma unroll
    for (int nf=0;nf<4;++nf) O[mf][nf] = fz;
  }

  const float kscale = 0.125f * 1.44269504088896340736f;
  size_t kvb = (size_t)(b*16 + h) * NP  * 64;   // pk (fp32 rows)
  size_t nb  = (size_t)(b*16 + h) * 512 * 64;   // knh/vnh (bf16 rows)
  size_t vtb = (size_t)(b*16 + h) * 64 * NP;    // vpT (bf16, d-major)
  int sj = tid >> 4, sd0 = (tid & 15) * 4;      // past-K / new-V pattern
  int nj = tid >> 3, nd0 = (tid & 7) * 8;       // new-K b128 pattern
  int vd = tid >> 3, vj8 = (tid & 7) * 8;       // vpT b128 pattern

  float4  kf4[4];      // past K fp32 regs; [0..1] reused as uint4 for new K
  uint4   vb2[2];      // past V^T bf16 regs
  ushort4 vn4[4];      // new V regs
  bool kp = false, vp2 = false;
  int kj0 = 0, vj0 = 0;

  auto issueK = [&](int it){
    kp = it < npast;
    kj0 = (kp ? it : it - npast) << 6;
    if (kp){
      #pragma unroll
      for (int i=0;i<4;++i)
        kf4[i] = *(const float4*)&pk[kvb + (size_t)(kj0 + sj + i*16)*64 + sd0];
    } else {
      #pragma unroll
      for (int i=0;i<2;++i)
        kf4[i] = __builtin_bit_cast(float4,
                   *(const uint4*)&knh[nb + (size_t)(kj0 + nj + i*32)*64 + nd0]);
    }
  };
  auto issueV = [&](int it){
    vp2 = it < npast;
    vj0 = (vp2 ? it : it - npast) << 6;
    if (vp2){
      #pragma unroll
      for (int i=0;i<2;++i)
        vb2[i] = *(const uint4*)&vpT[vtb + (size_t)(vd + i*32)*NP + vj0 + vj8];
    } else {
      #pragma unroll
      for (int i=0;i<4;++i)
        vn4[i] = *(const ushort4*)&vnh[nb + (size_t)(vj0 + sj + i*16)*64 + sd0];
    }
  };

  if (it0 < it1){ issueK(it0); issueV(it0); }

  for (int it = it0; it < it1; ++it){
    bool ispc = kp; int j0c = kj0;

    // ---- stage K tile from regs ----
    if (ispc){
      if (j0c + 64 <= Lp){
        #pragma unroll
        for (int i=0;i<4;++i){
          float4 kv = kf4[i];
          ushort4 kh4; kh4.x=cvt1(kv.x); kh4.y=cvt1(kv.y); kh4.z=cvt1(kv.z); kh4.w=cvt1(kv.w);
          *(ushort4*)&sK[(sj + i*16)*72 + sd0] = kh4;
        }
      } else {
        #pragma unroll
        for (int i=0;i<4;++i){
          int j = sj + i*16;
          float4 kv = kf4[i];
          if (j0c + j >= Lp){ kv.x=0.f; kv.y=0.f; kv.z=0.f; kv.w=0.f; }
          ushort4 kh4; kh4.x=cvt1(kv.x); kh4.y=cvt1(kv.y); kh4.z=cvt1(kv.z); kh4.w=cvt1(kv.w);
          *(ushort4*)&sK[j*72 + sd0] = kh4;
        }
      }
    } else {
      #pragma unroll
      for (int i=0;i<2;++i)
        *(uint4*)&sK[(nj + i*32)*72 + nd0] = __builtin_bit_cast(uint4, kf4[i]);
    }
    __syncthreads();                   // [A] staging visible; prev PV done

    if (it + 1 < it1) issueK(it + 1);  // EARLY issue: drains at next [A], a full iter away

    // ---- QK^T ----
    f32x4 Sc[2][4];
    #pragma unroll
    for (int mf=0;mf<2;++mf){
      #pragma unroll
      for (int jf=0;jf<4;++jf) Sc[mf][jf] = fz;
    }
    #pragma unroll
    for (int ks=0;ks<2;++ks){
      #pragma unroll
      for (int jf=0;jf<4;++jf){
        int off = (jf*16 + r)*72 + ks*32 + quad*8;
        bf16x8 kbh = *(const bf16x8*)&sK[off];
        #pragma unroll
        for (int mf=0;mf<2;++mf){
          Sc[mf][jf] = mfma16(Qh[mf][ks], kbh, Sc[mf][jf]);
          Sc[mf][jf] = mfma16(Ql[mf][ks], kbh, Sc[mf][jf]);
        }
      }
    }

    // ---- stage V^T (consumes V regs loaded last iter) ----
    if (vp2){
      #pragma unroll
      for (int i=0;i<2;++i)
        *(uint4*)&sVT[(vd + i*32)*72 + vj8] = vb2[i];
    } else {
      #pragma unroll
      for (int i=0;i<4;++i){
        int j = sj + i*16;
        sVT[(sd0+0)*72 + j] = vn4[i].x;
        sVT[(sd0+1)*72 + j] = vn4[i].y;
        sVT[(sd0+2)*72 + j] = vn4[i].z;
        sVT[(sd0+3)*72 + j] = vn4[i].w;
      }
    }
    if (it + 1 < it1) issueV(it + 1);  // early V issue (consumed next iter post-QK)

    // ---- fixed-max softmax: p = exp2(s*kscale - 4) ----
    int jlim = (ispc ? TL : Ln) - j0c;
    if (jlim >= 64){
      #pragma unroll
      for (int mf=0;mf<2;++mf){
        #pragma unroll
        for (int e=0;e<4;++e){
          int pbase = wid*2304 + (mf*16 + quad*4 + e)*72;
          float ls = 0.f;
          #pragma unroll
          for (int jf=0;jf<4;++jf){
            float pj = exp2f(Sc[mf][jf][e] * kscale - 4.0f);
            ls += pj;
            sP[pbase + jf*16 + r] = cvt1(pj);
          }
          lsum[mf][e] += ls;
        }
      }
    } else {
      #pragma unroll
      for (int mf=0;mf<2;++mf){
        #pragma unroll
        for (int e=0;e<4;++e){
          int pbase = wid*2304 + (mf*16 + quad*4 + e)*72;
          float ls = 0.f;
          #pragma unroll
          for (int jf=0;jf<4;++jf){
            float sv = Sc[mf][jf][e] * kscale - 4.0f;
            sv = (jf*16 + r < jlim) ? sv : -3.0e38f;
            float pj = exp2f(sv);
            ls += pj;
            sP[pbase + jf*16 + r] = cvt1(pj);
          }
          lsum[mf][e] += ls;
        }
      }
    }
    __syncthreads();                   // [B] sVT + sP visible; sK reads done

    // ---- O += P V ----
    #pragma unroll
    for (int ks=0;ks<2;++ks){
      bf16x8 pah[2];
      #pragma unroll
      for (int mf=0;mf<2;++mf){
        int off = wid*2304 + (mf*16 + r)*72 + ks*32 + quad*8;
        pah[mf] = *(const bf16x8*)&sP[off];
      }
      #pragma unroll
      for (int nf=0;nf<4;++nf){
        int off = (nf*16 + r)*72 + ks*32 + quad*8;
        bf16x8 vbh = *(const bf16x8*)&sVT[off];
        #pragma unroll
        for (int mf=0;mf<2;++mf){
          O[mf][nf] = mfma16(pah[mf], vbh, O[mf][nf]);
        }
      }
    }
  }

  // write partials: l (row sum over lanes) + un-normalized O (fp32)
  int pidx = ((b*16 + h)*4 + qt)*S + s;
  float* plr = pl + (size_t)pidx*128;
  float* po  = pO + (size_t)pidx*8192;
  float zadd = (s == 0) ? (float)Zar * 0.0625f : 0.f;
  #pragma unroll
  for (int mf=0;mf<2;++mf){
    #pragma unroll
    for (int e=0;e<4;++e){
      int row = wm0 + mf*16 + quad*4 + e;
      float l = lsum[mf][e];
      l += __shfl_xor(l, 1);
      l += __shfl_xor(l, 2);
      l += __shfl_xor(l, 4);
      l += __shfl_xor(l, 8);
      if (r == 0) plr[row] = l + zadd;
      #pragma unroll
      for (int nf=0;nf<4;++nf) po[row*64 + nf*16 + r] = O[mf][nf][e];
    }
  }
}

// ---------------- combine split-K partials (plain sum) ----------------
__global__ __launch_bounds__(256) void k_reduce(
    const float* __restrict__ pl, const float* __restrict__ pO,
    const int* __restrict__ plen, const int* __restrict__ cnts,
    int S, u16* __restrict__ aoh, u16* __restrict__ aol)
{
  int qt = blockIdx.x, h = blockIdx.y, b = blockIdx.z;
  int cnt = cnts[b]; int q0 = qt*128;
  if (q0 >= cnt) return;
  int Lp = min(max(plen[b], 0), NP);
  int TL = Lp + cnt;
  int Ln = max(0, TL - NP);
  int jend = min((Lp + 63) & ~63, NP);
  int minTLP = min(TL, NP);
  int Zar = max(0, minTLP - jend);
  int npast = jend >> 6, nnew = (Ln + 63) >> 6;
  int Tt = npast + nnew;
  int qsp = (Tt + S - 1) / S;

  int tid = threadIdx.x;
  int row = tid >> 1, c0 = (tid & 1) * 32;
  int base = ((b*16 + h)*4 + qt)*S;

  float L = 0.f;
  float acc[32];
  #pragma unroll
  for (int i=0;i<32;++i) acc[i] = 0.f;
  for (int s2=0;s2<S;++s2){
    bool act = (s2*qsp < Tt) || (s2 == 0 && Zar > 0);
    if (!act) continue;
    L += pl[(size_t)(base+s2)*128 + row];
    const float4* po = (const float4*)(pO + (size_t)(base+s2)*8192 + row*64 + c0);
    #pragma unroll
    for (int i=0;i<8;++i){
      float4 v = po[i];
      acc[4*i+0] += v.x; acc[4*i+1] += v.y; acc[4*i+2] += v.z; acc[4*i+3] += v.w;
    }
  }
  float inv = 1.f / L;
  size_t o = ((size_t)b*512 + q0 + row)*1024 + h*64 + c0;
  #pragma unroll
  for (int i=0;i<8;++i){
    ushort4 hv, lv;
    u16 hh, ll;
    split2(acc[4*i+0]*inv, hh, ll); hv.x=hh; lv.x=ll;
    split2(acc[4*i+1]*inv, hh, ll); hv.y=hh; lv.y=ll;
    split2(acc[4*i+2]*inv, hh, ll); hv.z=hh; lv.z=ll;
    split2(acc[4*i+3]*inv, hh, ll); hv.w=hh; lv.w=ll;
    *(ushort4*)&aoh[o + 4*i] = hv;
    *(ushort4*)&aol[o + 4*i] = lv;
  }
}

// ---------------- output projection GEMM + bias + mask ----------------
__global__ __launch_bounds__(256) void k_oproj(
    const u16* __restrict__ ah_, const u16* __restrict__ al_,
    const u16* __restrict__ Wth, const u16* __restrict__ Wtl,
    const float* __restrict__ bo, const int* __restrict__ cnts,
    float* __restrict__ out)
{
  int n0 = blockIdx.x * 128, m0 = blockIdx.y * 128;
  int b = m0 >> 9, t0 = m0 & 511;
  int cnt = cnts[b];
  int tid = threadIdx.x;
  if (t0 >= cnt){
    float4 z4 = {0.f,0.f,0.f,0.f};
    #pragma unroll
    for (int i=0;i<16;++i){
      int v = tid + i*256;
      int row = v >> 5, c4 = (v & 31) * 4;
      *(float4*)&out[(size_t)(m0+row)*1024 + n0 + c4] = z4;
    }
    return;
  }
  const u16* Bh = Wth + 3ull*1024*1024;
  const u16* Bl = Wtl + 3ull*1024*1024;

  __shared__ u16 sA[2][128*40];
  __shared__ u16 sB[2][128*40];

  int lane = tid & 63, wid = tid >> 6;
  int r = lane & 15, quad = lane >> 4;
  int wm = (wid >> 1) * 64, wn = (wid & 1) * 64;

  const f32x4 fz = {0.f,0.f,0.f,0.f};
  f32x4 acc[4][4];
  #pragma unroll
  for (int i=0;i<4;++i){
    #pragma unroll
    for (int j=0;j<4;++j) acc[i][j] = fz;
  }

  int srow = tid >> 2, sc8 = (tid & 3) * 8;

  for (int kt = 0; kt < 32; ++kt){
    int kb = kt * 32;
    __syncthreads();
    {
      size_t ga  = (size_t)(m0 + srow) * 1024 + kb + sc8;
      size_t gb  = (size_t)(n0 + srow) * 1024 + kb + sc8;
      int lo = srow*40 + sc8, lo2 = lo + 64*40;
      *(uint4*)&sA[0][lo]  = *(const uint4*)&ah_[ga];
      *(uint4*)&sA[1][lo]  = *(const uint4*)&al_[ga];
      *(uint4*)&sB[0][lo]  = *(const uint4*)&Bh[gb];
      *(uint4*)&sB[1][lo]  = *(const uint4*)&Bl[gb];
      *(uint4*)&sA[0][lo2] = *(const uint4*)&ah_[ga + 64*1024];
      *(uint4*)&sA[1][lo2] = *(const uint4*)&al_[ga + 64*1024];
      *(uint4*)&sB[0][lo2] = *(const uint4*)&Bh[gb + 64*1024];
      *(uint4*)&sB[1][lo2] = *(const uint4*)&Bl[gb + 64*1024];
    }
    __syncthreads();
    bf16x8 ah8[4], al8[4], bh8[4], bl8[4];
    #pragma unroll
    for (int mf=0; mf<4; ++mf){
      int off = (wm + mf*16 + r)*40 + quad*8;
      ah8[mf] = *(const bf16x8*)&sA[0][off];
      al8[mf] = *(const bf16x8*)&sA[1][off];
    }
    #pragma unroll
    for (int nf=0; nf<4; ++nf){
      int off = (wn + nf*16 + r)*40 + quad*8;
      bh8[nf] = *(const bf16x8*)&sB[0][off];
      bl8[nf] = *(const bf16x8*)&sB[1][off];
    }
    #pragma unroll
    for (int mf=0; mf<4; ++mf){
      #pragma unroll
      for (int nf=0; nf<4; ++nf){
        acc[mf][nf] = mfma16(ah8[mf], bh8[nf], acc[mf][nf]);
        acc[mf][nf] = mfma16(al8[mf], bh8[nf], acc[mf][nf]);
        acc[mf][nf] = mfma16(ah8[mf], bl8[nf], acc[mf][nf]);
      }
    }
  }

  #pragma unroll
  for (int mf=0;mf<4;++mf){
    #pragma unroll
    for (int e=0;e<4;++e){
      int t = t0 + wm + mf*16 + quad*4 + e;
      float msk = (t < cnt) ? 1.f : 0.f;
      int row = m0 + wm + mf*16 + quad*4 + e;
      #pragma unroll
      for (int nf=0;nf<4;++nf){
        int gc = n0 + wn + nf*16 + r;
        out[(size_t)row*1024 + gc] = (acc[mf][nf][e] + bo[gc]) * msk;
      }
    }
  }
}

extern "C" void kernel_launch(void* const* d_in, const int* in_sizes, int n_in,
                              void* d_out, int out_size, void* d_ws, size_t ws_size,
                              hipStream_t stream) {
  (void)in_sizes; (void)n_in; (void)out_size;
  const float* x    = (const float*)d_in[0];
  const float* rcos = (const float*)d_in[1];
  const float* rsin = (const float*)d_in[2];
  const float* pk   = (const float*)d_in[3];
  const float* pv   = (const float*)d_in[4];
  const int*   plen = (const int*)d_in[5];
  const int*   cnts = (const int*)d_in[7];
  const float* Wq = (const float*)d_in[8];
  const float* bq = (const float*)d_in[9];
  const float* Wk = (const float*)d_in[10];
  const float* bk = (const float*)d_in[11];
  const float* Wv = (const float*)d_in[12];
  const float* bv = (const float*)d_in[13];
  const float* Wo = (const float*)d_in[14];
  const float* bo = (const float*)d_in[15];
  float* out = (float*)d_out;

  char* w = (char*)d_ws;
  const size_t MB = 1024ull*1024;
  u16* xh  = (u16*)(w +   0*MB);    // aliased as attention-out hi after k_qkv
  u16* xl  = (u16*)(w +   8*MB);    // aliased as attention-out lo
  u16* Wth = (u16*)(w +  16*MB);
  u16* Wtl = (u16*)(w +  24*MB);
  u16* qh  = (u16*)(w +  32*MB);
  u16* ql  = (u16*)(w +  40*MB);
  u16* knh = (u16*)(w +  48*MB);
  u16* vnh = (u16*)(w +  56*MB);
  u16* vpT = (u16*)(w +  64*MB);    // 8*16*64*3584*2 = 56 MB
  float* pl = (float*)(w + 120*MB); // 512*S*128 f32 <= 2 MB
  float* pO = (float*)(w + 122*MB); // 512*S*8192 f32 = 16S MB
  u16* aoh = xh;
  u16* aol = xl;

  int S = (int)((ws_size - 122*MB) / (16*MB));
  if (S > 8) S = 8;
  if (S < 1) S = 1;

  k_split_x<<<dim3(4096), dim3(256), 0, stream>>>(x, xh, xl);
  k_wsplit<<<dim3(16,16,4), dim3(256), 0, stream>>>(Wq, Wk, Wv, Wo, Wth, Wtl);
  k_vcast<<<dim3(56,16,8), dim3(256), 0, stream>>>(pv, plen, vpT);
  k_qkv<<<dim3(8,32,3), dim3(256), 0, stream>>>(xh, xl, Wth, Wtl, bq, bk, bv,
                                                rcos, rsin, cnts,
                                                qh, ql, knh, vnh);
  k_attn<<<dim3(4,16,8*S), dim3(256), 0, stream>>>(qh, ql, knh, vnh,
                                                   pk, vpT, plen, cnts, S, pl, pO);
  k_reduce<<<dim3(4,16,8), dim3(256), 0, stream>>>(pl, pO, plen, cnts, S, aoh, aol);
  k_oproj<<<dim3(8,32), dim3(256), 0, stream>>>(aoh, aol, Wth, Wtl, bo, cnts, out);
}